// Round 2
// baseline (406.534 us; speedup 1.0000x reference)
//
#include <hip/hip_runtime.h>

// Problem constants (from reference): T=100 time steps, B=256, F=4096.
// Output: [B, T, F] float32, 419.4 MB. Write-bandwidth-bound.
constexpr int T = 100;
constexpr int B = 256;
constexpr int F = 4096;
constexpr int F4 = F / 4;   // float4 granularity along F

// Native clang vector type: __builtin_nontemporal_store requires a scalar or
// ext_vector_type pointer (HIP's float4 class is rejected). Same 16B layout.
typedef float floatx4 __attribute__((ext_vector_type(4)));

// One thread per (b, f4). Each thread computes 4 spike times, then streams
// T float4 stores down the time axis. Consecutive lanes -> consecutive f4,
// so each wave writes 1 KB contiguous per t step (global_store_dwordx4,
// fully coalesced).
__global__ __launch_bounds__(256) void spike_kernel(
    const float* __restrict__ x,
    const float* __restrict__ delays,
    float* __restrict__ out)
{
    const int idx = blockIdx.x * blockDim.x + threadIdx.x;  // 0 .. B*F4-1
    const int f4  = idx & (F4 - 1);
    const int b   = idx >> 10;  // idx / F4, F4 = 1024

    const floatx4 xv = reinterpret_cast<const floatx4*>(x)[idx];
    const floatx4 dv = reinterpret_cast<const floatx4*>(delays)[f4];

    // Match numpy float32 semantics exactly: separate mul / sub / mul with
    // round-to-nearest, NO fma contraction (hipcc default -ffp-contract=fast
    // would shift st by 1 near integer boundaries). Then trunc-toward-zero
    // cast (.astype(int32)) and clip to [0, T-1].
    auto spike_time = [](float xi, float di) -> int {
        float p  = __fmul_rn(xi, di);
        float s  = __fsub_rn(1.0f, p);
        float v  = __fmul_rn(s, 99.0f);   // (T-1) = 99
        int   st = (int)v;                 // trunc toward zero
        st = st < 0 ? 0 : st;
        st = st > (T - 1) ? (T - 1) : st;
        return st;
    };

    const int st0 = spike_time(xv.x, dv.x);
    const int st1 = spike_time(xv.y, dv.y);
    const int st2 = spike_time(xv.z, dv.z);
    const int st3 = spike_time(xv.w, dv.w);

    // out viewed as floatx4: [B, T, F4]; this thread owns column (b, :, f4)
    floatx4* outp = reinterpret_cast<floatx4*>(out) + (size_t)b * T * F4 + f4;

#pragma unroll 4
    for (int t = 0; t < T; ++t) {
        floatx4 v;
        v.x = (t == st0) ? 1.0f : 0.0f;
        v.y = (t == st1) ? 1.0f : 0.0f;
        v.z = (t == st2) ? 1.0f : 0.0f;
        v.w = (t == st3) ? 1.0f : 0.0f;
        // Output is write-only, 419 MB (> L3): stream past the caches.
        __builtin_nontemporal_store(v, outp + (size_t)t * F4);
    }
}

extern "C" void kernel_launch(void* const* d_in, const int* in_sizes, int n_in,
                              void* d_out, int out_size, void* d_ws, size_t ws_size,
                              hipStream_t stream)
{
    const float* x      = reinterpret_cast<const float*>(d_in[0]);   // [B, F]
    const float* delays = reinterpret_cast<const float*>(d_in[1]);   // [F]
    float* out          = reinterpret_cast<float*>(d_out);           // [B, T, F]

    const int n_threads = B * F4;          // 262144 threads, one per (b, f4)
    const int block = 256;
    const int grid  = n_threads / block;   // 1024 blocks -> 4 blocks/CU
    spike_kernel<<<grid, block, 0, stream>>>(x, delays, out);
}